// Round 8
// baseline (17361.101 us; speedup 1.0000x reference)
//
#include <hip/hip_runtime.h>

#define T_STEPS 2048
#define BATCH 8
#define HID 1024

// ws layout:
//   floats [0, 50331648)      x_proj repacked [b][t][gate][j]: ((b*2048+t)*3+g)*1024 + j
//   byte 201326592 (=192MiB): h double buffer, 2 x 4096 u64, each u64 packs the group's
//                             BATCH-PAIR at one j: slot = parity*4096 + group*1024 + j
//                             {hi = h[b0+1][j] clean, lo = h[b0][j] with bit30 = tag}.
//                             production step s -> parity s&1, tagbit(s) = ((s>>1)&1)^1.
//                             |h|<1 (clamped) => real bit30 == 0. ws poison 0xAAAAAAAA has
//                             bit30=0 != tagbit(0)=1, so poison never validates. 64 KiB.
//
// R8-domain64: the ledger isolates sync-domain size as dominant (per-step µs vs domain:
// 256->8.4, 128->5.1, 64->3.5, 32->4.3-confounded). Rebuild R1's 64-block-domain G=4
// geometry with R7's proven machinery: asm-streamed W (4 chunks x 12 dwordx4, 1-deep
// prefetch, counted vmcnt(12) waits — VGPR 56 in R7 proved no-spill), packed bit30-tagged
// u64 exchange (4 loads/thread), b128 LDS hv reads (8/lane vs R1's 128 scalar b32).
// 256-thread 4-wave blocks: 2 blocks/CU capacity at ANY VGPR<=256 (no R3/R4 zero-slack).
#define XPROJ_F 50331648ull
#define HBUF64_BYTE_OFF 201326592ull

typedef float f32x4 __attribute__((ext_vector_type(4)));

__device__ __forceinline__ float sigmoidf_(float x) {
    return 1.0f / (1.0f + __expf(-x));
}

// Relaxed AGENT-scope atomics lower to global_load/store ... sc1 — they read/
// write the Infinity Cache (the inter-XCD coherence point) with NO L2
// writeback/invalidate. An aligned 8B store is single-copy atomic, so the
// packed {tag|h_even, h_odd} packet is self-validating: no flags, no fences.
__device__ __forceinline__ unsigned long long ld_u64_agent(const unsigned long long* p) {
    return __hip_atomic_load(p, __ATOMIC_RELAXED, __HIP_MEMORY_SCOPE_AGENT);
}
__device__ __forceinline__ void st_u64_agent(unsigned long long* p, unsigned long long v) {
    __hip_atomic_store(p, v, __ATOMIC_RELAXED, __HIP_MEMORY_SCOPE_AGENT);
}

// inline-asm W load: asm volatile cannot be hoisted out of the t-loop (a normal
// load of the loop-invariant address would be hoisted then spilled — the R5/R6
// pathology). offset is a byte immediate (13-bit signed, <=4095 here).
#define LDW(dst, base, off)                                              \
    asm volatile("global_load_dwordx4 %0, %1, off offset:" #off          \
                 : "=v"(dst) : "v"(base) : "memory")

// one W chunk = rows {r,z,n} of j = jb_w+JJ, lane's 16 k as 4 dwordx4
#define ISSUE_CHUNK(BUF, JJ)                                             \
    do {                                                                 \
        const float* p0_ = w0 + (JJ) * 1024;                             \
        const float* p1_ = w1 + (JJ) * 1024;                             \
        const float* p2_ = w2 + (JJ) * 1024;                             \
        LDW(BUF[0][0], p0_, 0);    LDW(BUF[0][1], p0_, 1024);            \
        LDW(BUF[0][2], p0_, 2048); LDW(BUF[0][3], p0_, 3072);            \
        LDW(BUF[1][0], p1_, 0);    LDW(BUF[1][1], p1_, 1024);            \
        LDW(BUF[1][2], p1_, 2048); LDW(BUF[1][3], p1_, 3072);            \
        LDW(BUF[2][0], p2_, 0);    LDW(BUF[2][1], p2_, 1024);            \
        LDW(BUF[2][2], p2_, 2048); LDW(BUF[2][3], p2_, 3072);            \
    } while (0)

// consume one W chunk: 3 gates x 2 batches x 16 k = 96 FMA
#define FMA_CHUNK(BUF, JJ)                                               \
    do {                                                                 \
        _Pragma("unroll")                                                \
        for (int bb_ = 0; bb_ < 2; bb_++)                                \
            _Pragma("unroll")                                            \
            for (int m_ = 0; m_ < 4; m_++)                               \
                _Pragma("unroll")                                        \
                for (int e_ = 0; e_ < 4; e_++) {                         \
                    acc[0][(JJ) * 2 + bb_] = fmaf(BUF[0][m_][e_],        \
                        hv[bb_][m_][e_], acc[0][(JJ) * 2 + bb_]);        \
                    acc[1][(JJ) * 2 + bb_] = fmaf(BUF[1][m_][e_],        \
                        hv[bb_][m_][e_], acc[1][(JJ) * 2 + bb_]);        \
                    acc[2][(JJ) * 2 + bb_] = fmaf(BUF[2][m_][e_],        \
                        hv[bb_][m_][e_], acc[2][(JJ) * 2 + bb_]);        \
                }                                                        \
    } while (0)

// ---------------- Phase 1: x_proj = x @ W_ih^T + b_ih ----------------
// 128x128 tile, BK=16, 256 threads, 8x8 micro-tile. Epilogue writes the
// [b][t][g][j] layout the scan wants (j-contiguous -> two float4 stores/row).
__global__ __launch_bounds__(256) void gemm_xproj(
        const float* __restrict__ x, const float* __restrict__ Wih,
        const float* __restrict__ bih, float* __restrict__ xproj) {
    __shared__ float a_lds[16][128];  // [k][m]
    __shared__ float b_lds[16][128];  // [k][n]
    const int tid = threadIdx.x;
    const int m0 = blockIdx.x * 128;
    const int n0 = blockIdx.y * 128;
    const int tx = tid & 15, ty = tid >> 4;

    float acc[8][8];
#pragma unroll
    for (int i = 0; i < 8; i++)
#pragma unroll
        for (int jj = 0; jj < 8; jj++) acc[i][jj] = 0.f;

    for (int k0 = 0; k0 < 1024; k0 += 16) {
#pragma unroll
        for (int l = 0; l < 2; l++) {
            const int c = tid + l * 256;
            const int row = c >> 2;
            const int f4 = c & 3;
            float4 av = *reinterpret_cast<const float4*>(
                x + (size_t)(m0 + row) * 1024 + k0 + f4 * 4);
            float4 bv = *reinterpret_cast<const float4*>(
                Wih + (size_t)(n0 + row) * 1024 + k0 + f4 * 4);
            a_lds[f4 * 4 + 0][row] = av.x; a_lds[f4 * 4 + 1][row] = av.y;
            a_lds[f4 * 4 + 2][row] = av.z; a_lds[f4 * 4 + 3][row] = av.w;
            b_lds[f4 * 4 + 0][row] = bv.x; b_lds[f4 * 4 + 1][row] = bv.y;
            b_lds[f4 * 4 + 2][row] = bv.z; b_lds[f4 * 4 + 3][row] = bv.w;
        }
        __syncthreads();
#pragma unroll
        for (int kk = 0; kk < 16; kk++) {
            float a[8], b[8];
            *reinterpret_cast<float4*>(&a[0]) =
                *reinterpret_cast<float4*>(&a_lds[kk][ty * 8]);
            *reinterpret_cast<float4*>(&a[4]) =
                *reinterpret_cast<float4*>(&a_lds[kk][ty * 8 + 4]);
            *reinterpret_cast<float4*>(&b[0]) =
                *reinterpret_cast<float4*>(&b_lds[kk][tx * 8]);
            *reinterpret_cast<float4*>(&b[4]) =
                *reinterpret_cast<float4*>(&b_lds[kk][tx * 8 + 4]);
#pragma unroll
            for (int i = 0; i < 8; i++)
#pragma unroll
                for (int jj = 0; jj < 8; jj++)
                    acc[i][jj] = fmaf(a[i], b[jj], acc[i][jj]);
        }
        __syncthreads();
    }

    float bias[8];
    *reinterpret_cast<float4*>(&bias[0]) =
        *reinterpret_cast<const float4*>(bih + n0 + tx * 8);
    *reinterpret_cast<float4*>(&bias[4]) =
        *reinterpret_cast<const float4*>(bih + n0 + tx * 8 + 4);
    // m = b*T + t; 128-row m-tiles never straddle a batch (T=2048 % 128 == 0).
    // n-tile (128 wide) never straddles a gate (1024 % 128 == 0).
    const int n_base = n0 + tx * 8;
    const int g = n_base >> 10;
    const int j0 = n_base & 1023;
#pragma unroll
    for (int i = 0; i < 8; i++) {
        const int m = m0 + ty * 8 + i;
        const int b = m >> 11;        // m / 2048
        const int t = m & 2047;
        float* dst = xproj + (((size_t)b * 2048 + t) * 3 + g) * 1024 + j0;
        float4 r0 = {acc[i][0] + bias[0], acc[i][1] + bias[1],
                     acc[i][2] + bias[2], acc[i][3] + bias[3]};
        float4 r1 = {acc[i][4] + bias[4], acc[i][5] + bias[5],
                     acc[i][6] + bias[6], acc[i][7] + bias[7]};
        *reinterpret_cast<float4*>(dst) = r0;
        *reinterpret_cast<float4*>(dst + 4) = r1;
    }
}

// ---------------- Phase 2: sequential GRU scan, 64-block domains ----------------
// 256 blocks x 256 threads (4 waves). group = bid&3 (4 groups x 64 blocks) owns
// batches {2g, 2g+1} — independent sync domains of 64 blocks (the measured
// sweet spot). Block gb = bid>>2 owns j in [gb*16, gb*16+16); wave w owns 4 j
// (jb_w = gb*16 + w*4) for both batches. Lane c = lane&7: bb = lane&1,
// jj = (lane>>1)&3. Per lane: k-chunk {4L+256m+e}; 3 gates x 4 j x 2 b x 16 k
// = 384 FMA; W streamed per step as 4 jj-chunks x 12 asm dwordx4 with 1-deep
// prefetch and counted vmcnt(12) waits (in-order VM retirement makes the
// count exact even with gx loads outstanding). hv = 8 conflict-free
// ds_read_b128, held in regs across all 4 chunks.
// Per step: gx prefetch -> issue chunk0 -> 4 packed-tagged u64 poll ->
// unpack to LDS (dbuf) -> sync -> hv/hprev -> {issue next chunk, vmcnt(12),
// sched_barrier, FMA chunk} x4 -> 30-shuffle fold reduce -> gates ->
// 4 packed u64 + 8 out stores per wave.
__global__ __launch_bounds__(256, 2) void gru_scan(
        const float* __restrict__ Whh, const float* __restrict__ bhh,
        const float* __restrict__ xproj, float* __restrict__ out,
        unsigned long long* __restrict__ hbuf64) {
    __shared__ float hshare[2][2][HID];   // 16 KB, [parity][b_local][j]
    const int tid = threadIdx.x;
    const int bid = blockIdx.x;
    const int wave = tid >> 6;            // 0..3
    const int lane = tid & 63;
    const int group = bid & 3;            // 4 groups x 64 blocks
    const int gb = bid >> 2;              // block within group, 0..63
    const int b0 = group * 2;             // first of this group's 2 batches
    const int jb_w = gb * 16 + wave * 4;  // wave's first j

    const int bb_l = lane & 1;
    const int jj_l = (lane >> 1) & 3;
    const int j_l = jb_w + jj_l;
    const int b_l = b0 + bb_l;

    const float bh0 = bhh[j_l];
    const float bh1 = bhh[1024 + j_l];
    const float bh2 = bhh[2048 + j_l];
    const float CL = 0x1.fffffep-1f;   // largest float < 1: keeps bit30 == 0

    // W row bases (jj=0) for this wave's j block; lane's contiguous f4 chunk
    const float* w0 = Whh + (size_t)jb_w * 1024 + 4 * lane;
    const float* w1 = w0 + (size_t)1024 * 1024;
    const float* w2 = w1 + (size_t)1024 * 1024;

    // ---- t = 0: h_prev = 0 -> g_h = b_hh ----
    {
        const size_t xb = ((size_t)b_l * 2048 + 0) * 3072 + j_l;
        const float r = sigmoidf_(xproj[xb] + bh0);
        const float z = sigmoidf_(xproj[xb + 1024] + bh1);
        const float n = tanhf(xproj[xb + 2048] + r * bh2);
        float hnew = (1.f - z) * n;
        hnew = fminf(fmaxf(hnew, -CL), CL);
        const float hpair = __shfl_xor(hnew, 1);  // partner batch, same j
        const unsigned lo = __float_as_uint(hnew) | (1u << 30);  // tagbit(0)=1
        const unsigned hi = __float_as_uint(hpair);
        if (lane < 8 && (lane & 1) == 0)   // lanes 0,2,4,6 -> jj 0..3
            st_u64_agent(hbuf64 + (size_t)group * 1024 + j_l,
                         ((unsigned long long)hi << 32) | lo);
        if (lane < 8)
            out[((size_t)b_l * 2048) * 1024 + j_l] = hnew;
    }

    for (int t = 1; t < T_STEPS; t++) {
        // gx prefetch (cached loads, hidden under the staging/poll)
        const size_t xb = ((size_t)b_l * 2048 + t) * 3072 + j_l;
        const float gxr = xproj[xb];
        const float gxz = xproj[xb + 1024];
        const float gxn = xproj[xb + 2048];

        // W chunk 0 in flight during the poll
        f32x4 wA[3][4], wB[3][4];
        ISSUE_CHUNK(wA, 0);

        // ---- stage h(t-1): 4 packed tagged u64 loads per thread ----
        const int par = (t - 1) & 1;
        const unsigned long long* src =
            hbuf64 + (size_t)par * 4096 + (size_t)group * 1024;
        const unsigned expect = (((unsigned)(t - 1) >> 1) & 1u) ^ 1u;
        unsigned long long v[4];
#pragma unroll
        for (int i = 0; i < 4; i++)
            v[i] = ld_u64_agent(src + tid + 256 * i);
        for (;;) {
            unsigned bad = 0;
#pragma unroll
            for (int i = 0; i < 4; i++)
                bad |= (((unsigned)(v[i] >> 30)) & 1u) ^ expect;
            if (bad == 0) break;
            __builtin_amdgcn_s_sleep(1);
#pragma unroll
            for (int i = 0; i < 4; i++)
                if ((((unsigned)(v[i] >> 30)) & 1u) != expect)
                    v[i] = ld_u64_agent(src + tid + 256 * i);
        }
#pragma unroll
        for (int i = 0; i < 4; i++) {
            const int s = tid + 256 * i;    // slot = j
            hshare[par][0][s] = __uint_as_float((unsigned)v[i] & 0xBFFFFFFFu);
            hshare[par][1][s] = __uint_as_float((unsigned)(v[i] >> 32));
        }
        __syncthreads();   // whole block validated + staged h(t-1)
        // (no trailing barrier: next step stages into the other parity half)

        const float hprev = hshare[par][bb_l][j_l];

        // hv held in regs across all 4 W chunks: 8 ds_read_b128
        f32x4 hv[2][4];
#pragma unroll
        for (int bb = 0; bb < 2; bb++)
#pragma unroll
            for (int m = 0; m < 4; m++)
                hv[bb][m] = *reinterpret_cast<const f32x4*>(
                    &hshare[par][bb][4 * lane + 256 * m]);

        float acc[3][8];   // [g][jj*2+bb]
#pragma unroll
        for (int g = 0; g < 3; g++)
#pragma unroll
            for (int q = 0; q < 8; q++) acc[g][q] = 0.f;

        // ---- 4-chunk software pipeline; counted waits (never drain the
        // in-flight next chunk); sched_barrier fences reg-only FMAs from
        // hoisting past the asm waitcnt (rule #18) ----
        ISSUE_CHUNK(wB, 1);
        asm volatile("s_waitcnt vmcnt(12)" ::: "memory");
        __builtin_amdgcn_sched_barrier(0);
        FMA_CHUNK(wA, 0);
        ISSUE_CHUNK(wA, 2);
        asm volatile("s_waitcnt vmcnt(12)" ::: "memory");
        __builtin_amdgcn_sched_barrier(0);
        FMA_CHUNK(wB, 1);
        ISSUE_CHUNK(wB, 3);
        asm volatile("s_waitcnt vmcnt(12)" ::: "memory");
        __builtin_amdgcn_sched_barrier(0);
        FMA_CHUNK(wA, 2);
        asm volatile("s_waitcnt vmcnt(0)" ::: "memory");
        __builtin_amdgcn_sched_barrier(0);
        FMA_CHUNK(wB, 3);

        // ---- value-folding reduce over the 64-way K split ----
        // fold bb vs lane-bit0, jj-bit0 vs lane-bit1, jj-bit1 vs lane-bit2,
        // then butterflies 8/16/32; lane l ends with full sums for c = l&7.
        float a4[3][4];
#pragma unroll
        for (int g = 0; g < 3; g++)
#pragma unroll
            for (int k = 0; k < 4; k++) {
                const float e = acc[g][2 * k], o = acc[g][2 * k + 1];
                const float give = (lane & 1) ? e : o;
                const float keep = (lane & 1) ? o : e;
                a4[g][k] = keep + __shfl_xor(give, 1);
            }
        float a2[3][2];
#pragma unroll
        for (int g = 0; g < 3; g++)
#pragma unroll
            for (int k = 0; k < 2; k++) {
                const float e = a4[g][2 * k], o = a4[g][2 * k + 1];
                const float give = (lane & 2) ? e : o;
                const float keep = (lane & 2) ? o : e;
                a2[g][k] = keep + __shfl_xor(give, 2);
            }
        float a1[3];
#pragma unroll
        for (int g = 0; g < 3; g++) {
            const float e = a2[g][0], o = a2[g][1];
            const float give = (lane & 4) ? e : o;
            const float keep = (lane & 4) ? o : e;
            a1[g] = keep + __shfl_xor(give, 4);
        }
#pragma unroll
        for (int m = 8; m <= 32; m <<= 1)
#pragma unroll
            for (int g = 0; g < 3; g++) a1[g] += __shfl_xor(a1[g], m);

        // ---- gates on all lanes (a1 valid for c = lane&7 on every lane) ----
        const float r = sigmoidf_(gxr + a1[0] + bh0);
        const float z = sigmoidf_(gxz + a1[1] + bh1);
        const float n = tanhf(gxn + r * (a1[2] + bh2));
        float hnew = (1.f - z) * n + z * hprev;
        hnew = fminf(fmaxf(hnew, -CL), CL);
        const float hpair = __shfl_xor(hnew, 1);
        const unsigned tagst = (((unsigned)t >> 1) & 1u) ^ 1u;
        const unsigned lo = __float_as_uint(hnew) | (tagst << 30);
        const unsigned hi = __float_as_uint(hpair);
        if (lane < 8 && (lane & 1) == 0)
            st_u64_agent(hbuf64 + (size_t)(t & 1) * 4096 +
                             (size_t)group * 1024 + j_l,
                         ((unsigned long long)hi << 32) | lo);
        if (lane < 8)
            out[((size_t)b_l * 2048 + t) * 1024 + j_l] = hnew;
    }
}

extern "C" void kernel_launch(void* const* d_in, const int* in_sizes, int n_in,
                              void* d_out, int out_size, void* d_ws,
                              size_t ws_size, hipStream_t stream) {
    const float* x    = (const float*)d_in[0];
    const float* Wih  = (const float*)d_in[1];
    const float* bih  = (const float*)d_in[2];
    const float* Whh  = (const float*)d_in[3];
    const float* bhh  = (const float*)d_in[4];
    float* outp = (float*)d_out;

    float* xproj = (float*)d_ws;
    unsigned long long* hbuf64 =
        (unsigned long long*)((char*)d_ws + HBUF64_BYTE_OFF);

    dim3 g1(128, 24);   // M/128, N/128
    gemm_xproj<<<g1, 256, 0, stream>>>(x, Wih, bih, xproj);
    gru_scan<<<256, 256, 0, stream>>>(Whh, bhh, xproj, outp, hbuf64);
}

// Round 9
// 9313.729 us; speedup vs baseline: 1.8640x; 1.8640x over previous
//
#include <hip/hip_runtime.h>

#define T_STEPS 2048
#define BATCH 8
#define HID 1024

// ws layout:
//   floats [0, 50331648)      x_proj repacked [b][t][gate][j]: ((b*2048+t)*3+g)*1024 + j
//   byte 201326592 (=192MiB): h double buffer, 2 x 4096 u64, each u64 packs the group's
//                             BATCH-PAIR at one j: slot = parity*4096 + group*1024 + j
//                             {hi = h[b0+1][j] clean, lo = h[b0][j] with bit30 = tag}.
//                             production step s -> parity s&1, tagbit(s) = ((s>>1)&1)^1.
//                             |h|<1 (clamped) => real bit30 == 0. ws poison 0xAAAAAAAA has
//                             bit30=0 != tagbit(0)=1, so poison never validates. 64 KiB.
//
// R9-xcd-colocate: R8 was an accidental A/B on group ENCODING. With group=bid&3,
// same-j blocks (which read identical W rows) scatter to 4 different XCDs; per-XCD
// distinct W working set = 32 blocks x 192KB = 6MB > 4MB L2 -> thrash -> FETCH 50.7GB,
// 3.2TB/s, W-fetch-bound at VALUBusy 12% (16.2ms). R1's encoding group=bid>>6 puts the
// 4 same-gb blocks (bids gb, gb+64, gb+128, gb+192, all == gb mod 8) on ONE XCD ->
// 4-way W sharing, per-XCD set 8 slices x 192KB = 1.5MB < 4MB -> L2-resident (R1's
// FETCH: 0.8GB at the same 49MB/step stream). This round = R8 machinery (asm-streamed
// W 4-chunk vmcnt pipeline, packed bit30-tagged exchange, b128 LDS reads, 64-block
// domains) + the bid>>6 encoding. One variable changed vs R8.
#define XPROJ_F 50331648ull
#define HBUF64_BYTE_OFF 201326592ull

typedef float f32x4 __attribute__((ext_vector_type(4)));

__device__ __forceinline__ float sigmoidf_(float x) {
    return 1.0f / (1.0f + __expf(-x));
}

// Relaxed AGENT-scope atomics lower to global_load/store ... sc1 — they read/
// write the Infinity Cache (the inter-XCD coherence point) with NO L2
// writeback/invalidate. An aligned 8B store is single-copy atomic, so the
// packed {tag|h_even, h_odd} packet is self-validating: no flags, no fences.
__device__ __forceinline__ unsigned long long ld_u64_agent(const unsigned long long* p) {
    return __hip_atomic_load(p, __ATOMIC_RELAXED, __HIP_MEMORY_SCOPE_AGENT);
}
__device__ __forceinline__ void st_u64_agent(unsigned long long* p, unsigned long long v) {
    __hip_atomic_store(p, v, __ATOMIC_RELAXED, __HIP_MEMORY_SCOPE_AGENT);
}

// inline-asm W load: asm volatile cannot be hoisted out of the t-loop (a normal
// load of the loop-invariant address would be hoisted then spilled — the R5/R6
// pathology). offset is a byte immediate (13-bit signed, <=4095 here).
#define LDW(dst, base, off)                                              \
    asm volatile("global_load_dwordx4 %0, %1, off offset:" #off          \
                 : "=v"(dst) : "v"(base) : "memory")

// one W chunk = rows {r,z,n} of j = jb_w+JJ, lane's 16 k as 4 dwordx4
#define ISSUE_CHUNK(BUF, JJ)                                             \
    do {                                                                 \
        const float* p0_ = w0 + (JJ) * 1024;                             \
        const float* p1_ = w1 + (JJ) * 1024;                             \
        const float* p2_ = w2 + (JJ) * 1024;                             \
        LDW(BUF[0][0], p0_, 0);    LDW(BUF[0][1], p0_, 1024);            \
        LDW(BUF[0][2], p0_, 2048); LDW(BUF[0][3], p0_, 3072);            \
        LDW(BUF[1][0], p1_, 0);    LDW(BUF[1][1], p1_, 1024);            \
        LDW(BUF[1][2], p1_, 2048); LDW(BUF[1][3], p1_, 3072);            \
        LDW(BUF[2][0], p2_, 0);    LDW(BUF[2][1], p2_, 1024);            \
        LDW(BUF[2][2], p2_, 2048); LDW(BUF[2][3], p2_, 3072);            \
    } while (0)

// consume one W chunk: 3 gates x 2 batches x 16 k = 96 FMA
#define FMA_CHUNK(BUF, JJ)                                               \
    do {                                                                 \
        _Pragma("unroll")                                                \
        for (int bb_ = 0; bb_ < 2; bb_++)                                \
            _Pragma("unroll")                                            \
            for (int m_ = 0; m_ < 4; m_++)                               \
                _Pragma("unroll")                                        \
                for (int e_ = 0; e_ < 4; e_++) {                         \
                    acc[0][(JJ) * 2 + bb_] = fmaf(BUF[0][m_][e_],        \
                        hv[bb_][m_][e_], acc[0][(JJ) * 2 + bb_]);        \
                    acc[1][(JJ) * 2 + bb_] = fmaf(BUF[1][m_][e_],        \
                        hv[bb_][m_][e_], acc[1][(JJ) * 2 + bb_]);        \
                    acc[2][(JJ) * 2 + bb_] = fmaf(BUF[2][m_][e_],        \
                        hv[bb_][m_][e_], acc[2][(JJ) * 2 + bb_]);        \
                }                                                        \
    } while (0)

// ---------------- Phase 1: x_proj = x @ W_ih^T + b_ih ----------------
// 128x128 tile, BK=16, 256 threads, 8x8 micro-tile. Epilogue writes the
// [b][t][g][j] layout the scan wants (j-contiguous -> two float4 stores/row).
__global__ __launch_bounds__(256) void gemm_xproj(
        const float* __restrict__ x, const float* __restrict__ Wih,
        const float* __restrict__ bih, float* __restrict__ xproj) {
    __shared__ float a_lds[16][128];  // [k][m]
    __shared__ float b_lds[16][128];  // [k][n]
    const int tid = threadIdx.x;
    const int m0 = blockIdx.x * 128;
    const int n0 = blockIdx.y * 128;
    const int tx = tid & 15, ty = tid >> 4;

    float acc[8][8];
#pragma unroll
    for (int i = 0; i < 8; i++)
#pragma unroll
        for (int jj = 0; jj < 8; jj++) acc[i][jj] = 0.f;

    for (int k0 = 0; k0 < 1024; k0 += 16) {
#pragma unroll
        for (int l = 0; l < 2; l++) {
            const int c = tid + l * 256;
            const int row = c >> 2;
            const int f4 = c & 3;
            float4 av = *reinterpret_cast<const float4*>(
                x + (size_t)(m0 + row) * 1024 + k0 + f4 * 4);
            float4 bv = *reinterpret_cast<const float4*>(
                Wih + (size_t)(n0 + row) * 1024 + k0 + f4 * 4);
            a_lds[f4 * 4 + 0][row] = av.x; a_lds[f4 * 4 + 1][row] = av.y;
            a_lds[f4 * 4 + 2][row] = av.z; a_lds[f4 * 4 + 3][row] = av.w;
            b_lds[f4 * 4 + 0][row] = bv.x; b_lds[f4 * 4 + 1][row] = bv.y;
            b_lds[f4 * 4 + 2][row] = bv.z; b_lds[f4 * 4 + 3][row] = bv.w;
        }
        __syncthreads();
#pragma unroll
        for (int kk = 0; kk < 16; kk++) {
            float a[8], b[8];
            *reinterpret_cast<float4*>(&a[0]) =
                *reinterpret_cast<float4*>(&a_lds[kk][ty * 8]);
            *reinterpret_cast<float4*>(&a[4]) =
                *reinterpret_cast<float4*>(&a_lds[kk][ty * 8 + 4]);
            *reinterpret_cast<float4*>(&b[0]) =
                *reinterpret_cast<float4*>(&b_lds[kk][tx * 8]);
            *reinterpret_cast<float4*>(&b[4]) =
                *reinterpret_cast<float4*>(&b_lds[kk][tx * 8 + 4]);
#pragma unroll
            for (int i = 0; i < 8; i++)
#pragma unroll
                for (int jj = 0; jj < 8; jj++)
                    acc[i][jj] = fmaf(a[i], b[jj], acc[i][jj]);
        }
        __syncthreads();
    }

    float bias[8];
    *reinterpret_cast<float4*>(&bias[0]) =
        *reinterpret_cast<const float4*>(bih + n0 + tx * 8);
    *reinterpret_cast<float4*>(&bias[4]) =
        *reinterpret_cast<const float4*>(bih + n0 + tx * 8 + 4);
    // m = b*T + t; 128-row m-tiles never straddle a batch (T=2048 % 128 == 0).
    // n-tile (128 wide) never straddles a gate (1024 % 128 == 0).
    const int n_base = n0 + tx * 8;
    const int g = n_base >> 10;
    const int j0 = n_base & 1023;
#pragma unroll
    for (int i = 0; i < 8; i++) {
        const int m = m0 + ty * 8 + i;
        const int b = m >> 11;        // m / 2048
        const int t = m & 2047;
        float* dst = xproj + (((size_t)b * 2048 + t) * 3 + g) * 1024 + j0;
        float4 r0 = {acc[i][0] + bias[0], acc[i][1] + bias[1],
                     acc[i][2] + bias[2], acc[i][3] + bias[3]};
        float4 r1 = {acc[i][4] + bias[4], acc[i][5] + bias[5],
                     acc[i][6] + bias[6], acc[i][7] + bias[7]};
        *reinterpret_cast<float4*>(dst) = r0;
        *reinterpret_cast<float4*>(dst + 4) = r1;
    }
}

// ---------------- Phase 2: sequential GRU scan, 64-block XCD-aligned domains ----
// 256 blocks x 256 threads (4 waves). group = bid>>6 (4 groups x 64 blocks) owns
// batches {2g, 2g+1}; gb = bid&63. Same-gb blocks of the 4 groups (bids gb+64g,
// all == gb mod 8) land on ONE XCD under round-robin dispatch -> they share their
// W rows in that XCD's L2; per-XCD distinct W set = 8 slices x 192KB = 1.5MB
// (L2-resident). Block owns j in [gb*16, gb*16+16); wave w owns 4 j for both
// batches. Lane c = lane&7: bb = lane&1, jj = (lane>>1)&3. Per lane: k-chunk
// {4L+256m+e}; 384 FMA; W streamed per step as 4 jj-chunks x 12 asm dwordx4,
// 1-deep prefetch, counted vmcnt(12) waits. hv = 8 conflict-free ds_read_b128.
// Per step: gx prefetch -> issue chunk0 -> 4 packed-tagged u64 poll -> unpack
// to LDS (dbuf) -> sync -> hv/hprev -> {issue next, vmcnt(12), sched_barrier,
// FMA} x4 -> 30-shuffle fold reduce -> gates -> 4 packed u64 + 8 out stores/wave.
__global__ __launch_bounds__(256, 2) void gru_scan(
        const float* __restrict__ Whh, const float* __restrict__ bhh,
        const float* __restrict__ xproj, float* __restrict__ out,
        unsigned long long* __restrict__ hbuf64) {
    __shared__ float hshare[2][2][HID];   // 16 KB, [parity][b_local][j]
    const int tid = threadIdx.x;
    const int bid = blockIdx.x;
    const int wave = tid >> 6;            // 0..3
    const int lane = tid & 63;
    const int group = bid >> 6;           // 4 groups x 64 blocks (XCD-aligned)
    const int gb = bid & 63;              // block within group
    const int b0 = group * 2;             // first of this group's 2 batches
    const int jb_w = gb * 16 + wave * 4;  // wave's first j

    const int bb_l = lane & 1;
    const int jj_l = (lane >> 1) & 3;
    const int j_l = jb_w + jj_l;
    const int b_l = b0 + bb_l;

    const float bh0 = bhh[j_l];
    const float bh1 = bhh[1024 + j_l];
    const float bh2 = bhh[2048 + j_l];
    const float CL = 0x1.fffffep-1f;   // largest float < 1: keeps bit30 == 0

    // W row bases (jj=0) for this wave's j block; lane's contiguous f4 chunk
    const float* w0 = Whh + (size_t)jb_w * 1024 + 4 * lane;
    const float* w1 = w0 + (size_t)1024 * 1024;
    const float* w2 = w1 + (size_t)1024 * 1024;

    // ---- t = 0: h_prev = 0 -> g_h = b_hh ----
    {
        const size_t xb = ((size_t)b_l * 2048 + 0) * 3072 + j_l;
        const float r = sigmoidf_(xproj[xb] + bh0);
        const float z = sigmoidf_(xproj[xb + 1024] + bh1);
        const float n = tanhf(xproj[xb + 2048] + r * bh2);
        float hnew = (1.f - z) * n;
        hnew = fminf(fmaxf(hnew, -CL), CL);
        const float hpair = __shfl_xor(hnew, 1);  // partner batch, same j
        const unsigned lo = __float_as_uint(hnew) | (1u << 30);  // tagbit(0)=1
        const unsigned hi = __float_as_uint(hpair);
        if (lane < 8 && (lane & 1) == 0)   // lanes 0,2,4,6 -> jj 0..3
            st_u64_agent(hbuf64 + (size_t)group * 1024 + j_l,
                         ((unsigned long long)hi << 32) | lo);
        if (lane < 8)
            out[((size_t)b_l * 2048) * 1024 + j_l] = hnew;
    }

    for (int t = 1; t < T_STEPS; t++) {
        // gx prefetch (cached loads, hidden under the staging/poll)
        const size_t xb = ((size_t)b_l * 2048 + t) * 3072 + j_l;
        const float gxr = xproj[xb];
        const float gxz = xproj[xb + 1024];
        const float gxn = xproj[xb + 2048];

        // W chunk 0 in flight during the poll
        f32x4 wA[3][4], wB[3][4];
        ISSUE_CHUNK(wA, 0);

        // ---- stage h(t-1): 4 packed tagged u64 loads per thread ----
        const int par = (t - 1) & 1;
        const unsigned long long* src =
            hbuf64 + (size_t)par * 4096 + (size_t)group * 1024;
        const unsigned expect = (((unsigned)(t - 1) >> 1) & 1u) ^ 1u;
        unsigned long long v[4];
#pragma unroll
        for (int i = 0; i < 4; i++)
            v[i] = ld_u64_agent(src + tid + 256 * i);
        for (;;) {
            unsigned bad = 0;
#pragma unroll
            for (int i = 0; i < 4; i++)
                bad |= (((unsigned)(v[i] >> 30)) & 1u) ^ expect;
            if (bad == 0) break;
            __builtin_amdgcn_s_sleep(1);
#pragma unroll
            for (int i = 0; i < 4; i++)
                if ((((unsigned)(v[i] >> 30)) & 1u) != expect)
                    v[i] = ld_u64_agent(src + tid + 256 * i);
        }
#pragma unroll
        for (int i = 0; i < 4; i++) {
            const int s = tid + 256 * i;    // slot = j
            hshare[par][0][s] = __uint_as_float((unsigned)v[i] & 0xBFFFFFFFu);
            hshare[par][1][s] = __uint_as_float((unsigned)(v[i] >> 32));
        }
        __syncthreads();   // whole block validated + staged h(t-1)
        // (no trailing barrier: next step stages into the other parity half)

        const float hprev = hshare[par][bb_l][j_l];

        // hv held in regs across all 4 W chunks: 8 ds_read_b128
        f32x4 hv[2][4];
#pragma unroll
        for (int bb = 0; bb < 2; bb++)
#pragma unroll
            for (int m = 0; m < 4; m++)
                hv[bb][m] = *reinterpret_cast<const f32x4*>(
                    &hshare[par][bb][4 * lane + 256 * m]);

        float acc[3][8];   // [g][jj*2+bb]
#pragma unroll
        for (int g = 0; g < 3; g++)
#pragma unroll
            for (int q = 0; q < 8; q++) acc[g][q] = 0.f;

        // ---- 4-chunk software pipeline; counted waits (never drain the
        // in-flight next chunk); sched_barrier fences reg-only FMAs from
        // hoisting past the asm waitcnt (rule #18) ----
        ISSUE_CHUNK(wB, 1);
        asm volatile("s_waitcnt vmcnt(12)" ::: "memory");
        __builtin_amdgcn_sched_barrier(0);
        FMA_CHUNK(wA, 0);
        ISSUE_CHUNK(wA, 2);
        asm volatile("s_waitcnt vmcnt(12)" ::: "memory");
        __builtin_amdgcn_sched_barrier(0);
        FMA_CHUNK(wB, 1);
        ISSUE_CHUNK(wB, 3);
        asm volatile("s_waitcnt vmcnt(12)" ::: "memory");
        __builtin_amdgcn_sched_barrier(0);
        FMA_CHUNK(wA, 2);
        asm volatile("s_waitcnt vmcnt(0)" ::: "memory");
        __builtin_amdgcn_sched_barrier(0);
        FMA_CHUNK(wB, 3);

        // ---- value-folding reduce over the 64-way K split ----
        // fold bb vs lane-bit0, jj-bit0 vs lane-bit1, jj-bit1 vs lane-bit2,
        // then butterflies 8/16/32; lane l ends with full sums for c = l&7.
        float a4[3][4];
#pragma unroll
        for (int g = 0; g < 3; g++)
#pragma unroll
            for (int k = 0; k < 4; k++) {
                const float e = acc[g][2 * k], o = acc[g][2 * k + 1];
                const float give = (lane & 1) ? e : o;
                const float keep = (lane & 1) ? o : e;
                a4[g][k] = keep + __shfl_xor(give, 1);
            }
        float a2[3][2];
#pragma unroll
        for (int g = 0; g < 3; g++)
#pragma unroll
            for (int k = 0; k < 2; k++) {
                const float e = a4[g][2 * k], o = a4[g][2 * k + 1];
                const float give = (lane & 2) ? e : o;
                const float keep = (lane & 2) ? o : e;
                a2[g][k] = keep + __shfl_xor(give, 2);
            }
        float a1[3];
#pragma unroll
        for (int g = 0; g < 3; g++) {
            const float e = a2[g][0], o = a2[g][1];
            const float give = (lane & 4) ? e : o;
            const float keep = (lane & 4) ? o : e;
            a1[g] = keep + __shfl_xor(give, 4);
        }
#pragma unroll
        for (int m = 8; m <= 32; m <<= 1)
#pragma unroll
            for (int g = 0; g < 3; g++) a1[g] += __shfl_xor(a1[g], m);

        // ---- gates on all lanes (a1 valid for c = lane&7 on every lane) ----
        const float r = sigmoidf_(gxr + a1[0] + bh0);
        const float z = sigmoidf_(gxz + a1[1] + bh1);
        const float n = tanhf(gxn + r * (a1[2] + bh2));
        float hnew = (1.f - z) * n + z * hprev;
        hnew = fminf(fmaxf(hnew, -CL), CL);
        const float hpair = __shfl_xor(hnew, 1);
        const unsigned tagst = (((unsigned)t >> 1) & 1u) ^ 1u;
        const unsigned lo = __float_as_uint(hnew) | (tagst << 30);
        const unsigned hi = __float_as_uint(hpair);
        if (lane < 8 && (lane & 1) == 0)
            st_u64_agent(hbuf64 + (size_t)(t & 1) * 4096 +
                             (size_t)group * 1024 + j_l,
                         ((unsigned long long)hi << 32) | lo);
        if (lane < 8)
            out[((size_t)b_l * 2048 + t) * 1024 + j_l] = hnew;
    }
}

extern "C" void kernel_launch(void* const* d_in, const int* in_sizes, int n_in,
                              void* d_out, int out_size, void* d_ws,
                              size_t ws_size, hipStream_t stream) {
    const float* x    = (const float*)d_in[0];
    const float* Wih  = (const float*)d_in[1];
    const float* bih  = (const float*)d_in[2];
    const float* Whh  = (const float*)d_in[3];
    const float* bhh  = (const float*)d_in[4];
    float* outp = (float*)d_out;

    float* xproj = (float*)d_ws;
    unsigned long long* hbuf64 =
        (unsigned long long*)((char*)d_ws + HBUF64_BYTE_OFF);

    dim3 g1(128, 24);   // M/128, N/128
    gemm_xproj<<<g1, 256, 0, stream>>>(x, Wih, bih, xproj);
    gru_scan<<<256, 256, 0, stream>>>(Whh, bhh, xproj, outp, hbuf64);
}

// Round 11
// 7574.779 us; speedup vs baseline: 2.2920x; 1.2296x over previous
//
#include <hip/hip_runtime.h>

#define T_STEPS 2048
#define BATCH 8
#define HID 1024

// ws layout:
//   floats [0, 50331648)      x_proj repacked [b][t][gate][j]: ((b*2048+t)*3+g)*1024 + j
//   byte 201326592 (=192MiB): h double buffer, 2 x 4096 u64, each u64 packs the group's
//                             BATCH-PAIR at one j: slot = parity*4096 + group*1024 + j
//                             {hi = h[b0+1][j] clean, lo = h[b0][j] with bit30 = tag}.
//                             production step s -> parity s&1, tagbit(s) = ((s>>1)&1)^1.
//                             |h|<1 (clamped) => real bit30 == 0. ws poison 0xAAAAAAAA has
//                             bit30=0 != tagbit(0)=1, so poison never validates. 64 KiB.
//
// R11 = R10 resubmitted after hang-audit (attributed to infra: no deadlock mechanism
// exists — exchange protocol identical to R9 which ran; 2-blocks/CU capacity, not
// R3/R4's zero-slack shape; plain sunk loads can be slow, never hang).
//
// R10-unfence theory: R9 confirmed XCD co-location (FETCH 50.7GB -> 0.54GB) but ran
// 4.1 µs/step vs R1's 3.5 — at 1 wave/SIMD (zero TLP) the hand-fenced W pipeline's
// 4 per-step {s_waitcnt + sched_barrier(0)} pairs are fully-exposed stalls and forbid
// the compiler from interleaving poll/hv/W-latency/reduce. R1 proved plain pre-loop W
// loads get SUNK into the t-loop (VGPR 132, no spill) and freely scheduled. This round:
// R9 minus the asm machinery; wf = plain f32x4 loads declared pre-loop (compiler sinks
// -> in-loop dwordx4 from L2, 48/lane/step vs R1's 192 scalar), hv = 8 b128 LDS reads,
// packed exchange, XCD-aligned encoding. Single variable changed vs R9.
#define XPROJ_F 50331648ull
#define HBUF64_BYTE_OFF 201326592ull

typedef float f32x4 __attribute__((ext_vector_type(4)));

__device__ __forceinline__ float sigmoidf_(float x) {
    return 1.0f / (1.0f + __expf(-x));
}

// Relaxed AGENT-scope atomics lower to global_load/store ... sc1 — they read/
// write the Infinity Cache (the inter-XCD coherence point) with NO L2
// writeback/invalidate. An aligned 8B store is single-copy atomic, so the
// packed {tag|h_even, h_odd} packet is self-validating: no flags, no fences.
__device__ __forceinline__ unsigned long long ld_u64_agent(const unsigned long long* p) {
    return __hip_atomic_load(p, __ATOMIC_RELAXED, __HIP_MEMORY_SCOPE_AGENT);
}
__device__ __forceinline__ void st_u64_agent(unsigned long long* p, unsigned long long v) {
    __hip_atomic_store(p, v, __ATOMIC_RELAXED, __HIP_MEMORY_SCOPE_AGENT);
}

// ---------------- Phase 1: x_proj = x @ W_ih^T + b_ih ----------------
// 128x128 tile, BK=16, 256 threads, 8x8 micro-tile. Epilogue writes the
// [b][t][g][j] layout the scan wants (j-contiguous -> two float4 stores/row).
__global__ __launch_bounds__(256) void gemm_xproj(
        const float* __restrict__ x, const float* __restrict__ Wih,
        const float* __restrict__ bih, float* __restrict__ xproj) {
    __shared__ float a_lds[16][128];  // [k][m]
    __shared__ float b_lds[16][128];  // [k][n]
    const int tid = threadIdx.x;
    const int m0 = blockIdx.x * 128;
    const int n0 = blockIdx.y * 128;
    const int tx = tid & 15, ty = tid >> 4;

    float acc[8][8];
#pragma unroll
    for (int i = 0; i < 8; i++)
#pragma unroll
        for (int jj = 0; jj < 8; jj++) acc[i][jj] = 0.f;

    for (int k0 = 0; k0 < 1024; k0 += 16) {
#pragma unroll
        for (int l = 0; l < 2; l++) {
            const int c = tid + l * 256;
            const int row = c >> 2;
            const int f4 = c & 3;
            float4 av = *reinterpret_cast<const float4*>(
                x + (size_t)(m0 + row) * 1024 + k0 + f4 * 4);
            float4 bv = *reinterpret_cast<const float4*>(
                Wih + (size_t)(n0 + row) * 1024 + k0 + f4 * 4);
            a_lds[f4 * 4 + 0][row] = av.x; a_lds[f4 * 4 + 1][row] = av.y;
            a_lds[f4 * 4 + 2][row] = av.z; a_lds[f4 * 4 + 3][row] = av.w;
            b_lds[f4 * 4 + 0][row] = bv.x; b_lds[f4 * 4 + 1][row] = bv.y;
            b_lds[f4 * 4 + 2][row] = bv.z; b_lds[f4 * 4 + 3][row] = bv.w;
        }
        __syncthreads();
#pragma unroll
        for (int kk = 0; kk < 16; kk++) {
            float a[8], b[8];
            *reinterpret_cast<float4*>(&a[0]) =
                *reinterpret_cast<float4*>(&a_lds[kk][ty * 8]);
            *reinterpret_cast<float4*>(&a[4]) =
                *reinterpret_cast<float4*>(&a_lds[kk][ty * 8 + 4]);
            *reinterpret_cast<float4*>(&b[0]) =
                *reinterpret_cast<float4*>(&b_lds[kk][tx * 8]);
            *reinterpret_cast<float4*>(&b[4]) =
                *reinterpret_cast<float4*>(&b_lds[kk][tx * 8 + 4]);
#pragma unroll
            for (int i = 0; i < 8; i++)
#pragma unroll
                for (int jj = 0; jj < 8; jj++)
                    acc[i][jj] = fmaf(a[i], b[jj], acc[i][jj]);
        }
        __syncthreads();
    }

    float bias[8];
    *reinterpret_cast<float4*>(&bias[0]) =
        *reinterpret_cast<const float4*>(bih + n0 + tx * 8);
    *reinterpret_cast<float4*>(&bias[4]) =
        *reinterpret_cast<const float4*>(bih + n0 + tx * 8 + 4);
    // m = b*T + t; 128-row m-tiles never straddle a batch (T=2048 % 128 == 0).
    // n-tile (128 wide) never straddles a gate (1024 % 128 == 0).
    const int n_base = n0 + tx * 8;
    const int g = n_base >> 10;
    const int j0 = n_base & 1023;
#pragma unroll
    for (int i = 0; i < 8; i++) {
        const int m = m0 + ty * 8 + i;
        const int b = m >> 11;        // m / 2048
        const int t = m & 2047;
        float* dst = xproj + (((size_t)b * 2048 + t) * 3 + g) * 1024 + j0;
        float4 r0 = {acc[i][0] + bias[0], acc[i][1] + bias[1],
                     acc[i][2] + bias[2], acc[i][3] + bias[3]};
        float4 r1 = {acc[i][4] + bias[4], acc[i][5] + bias[5],
                     acc[i][6] + bias[6], acc[i][7] + bias[7]};
        *reinterpret_cast<float4*>(dst) = r0;
        *reinterpret_cast<float4*>(dst + 4) = r1;
    }
}

// ---------------- Phase 2: sequential GRU scan, 64-block XCD-aligned domains ----
// 256 blocks x 256 threads (4 waves). group = bid>>6 (4 groups x 64 blocks) owns
// batches {2g, 2g+1}; gb = bid&63. Same-gb blocks of the 4 groups (bids gb+64g,
// all == gb mod 8) land on ONE XCD under round-robin dispatch -> they share their
// W rows in that XCD's L2; per-XCD distinct W set = 8 slices x 192KB = 1.5MB
// (L2-resident; R9 verified: FETCH 0.54GB). Block owns j in [gb*16, gb*16+16);
// wave w owns 4 j for both batches. Lane c = lane&7: bb = lane&1, jj = (lane>>1)&3.
// Per lane: k-chunk {4L+256m+e}; 384 FMA; W = plain pre-loop f32x4 loads, SUNK by
// the compiler into the t-loop (R1-proven: no spill, free scheduling, in-loop
// dwordx4 from L2 overlapped with poll/LDS/reduce). hv = 8 conflict-free
// ds_read_b128, held in regs across the matvec.
// Per step: gx prefetch -> 4 packed-tagged u64 poll -> unpack to LDS (dbuf) ->
// sync -> hv/hprev -> matvec (compiler-scheduled W loads + 384 FMA) ->
// 30-shuffle fold reduce -> gates -> 4 packed u64 + 8 out stores per wave.
__global__ __launch_bounds__(256, 2) void gru_scan(
        const float* __restrict__ Whh, const float* __restrict__ bhh,
        const float* __restrict__ xproj, float* __restrict__ out,
        unsigned long long* __restrict__ hbuf64) {
    __shared__ float hshare[2][2][HID];   // 16 KB, [parity][b_local][j]
    const int tid = threadIdx.x;
    const int bid = blockIdx.x;
    const int wave = tid >> 6;            // 0..3
    const int lane = tid & 63;
    const int group = bid >> 6;           // 4 groups x 64 blocks (XCD-aligned)
    const int gb = bid & 63;              // block within group
    const int b0 = group * 2;             // first of this group's 2 batches
    const int jb_w = gb * 16 + wave * 4;  // wave's first j

    const int bb_l = lane & 1;
    const int jj_l = (lane >> 1) & 3;
    const int j_l = jb_w + jj_l;
    const int b_l = b0 + bb_l;

    const float bh0 = bhh[j_l];
    const float bh1 = bhh[1024 + j_l];
    const float bh2 = bhh[2048 + j_l];
    const float CL = 0x1.fffffep-1f;   // largest float < 1: keeps bit30 == 0

    // W fragment, PLAIN loads declared pre-loop: rows g*1024 + (jb_w+jj),
    // lane's contiguous 16-k chunk {4L+256m+e} as f32x4. The live set
    // (48 f4 = 192 regs) exceeds the (256,2) 128-VGPR budget, so the
    // allocator SINKS these loads into the t-loop (R1-verified behavior,
    // VGPR 132) — emitted as in-loop global_load_dwordx4 from the
    // XCD-resident L2, freely scheduled. Do NOT volatile/asm-pin
    // (R5/R6: scratch spill; R9: fence serialization at 1 wave/SIMD).
    f32x4 wf[3][4][4];   // [gate][jj][m]
#pragma unroll
    for (int g = 0; g < 3; g++)
#pragma unroll
        for (int jj = 0; jj < 4; jj++)
#pragma unroll
            for (int m = 0; m < 4; m++)
                wf[g][jj][m] = *reinterpret_cast<const f32x4*>(
                    Whh + (size_t)(g * 1024 + jb_w + jj) * 1024 +
                    4 * lane + 256 * m);

    // ---- t = 0: h_prev = 0 -> g_h = b_hh ----
    {
        const size_t xb = ((size_t)b_l * 2048 + 0) * 3072 + j_l;
        const float r = sigmoidf_(xproj[xb] + bh0);
        const float z = sigmoidf_(xproj[xb + 1024] + bh1);
        const float n = tanhf(xproj[xb + 2048] + r * bh2);
        float hnew = (1.f - z) * n;
        hnew = fminf(fmaxf(hnew, -CL), CL);
        const float hpair = __shfl_xor(hnew, 1);  // partner batch, same j
        const unsigned lo = __float_as_uint(hnew) | (1u << 30);  // tagbit(0)=1
        const unsigned hi = __float_as_uint(hpair);
        if (lane < 8 && (lane & 1) == 0)   // lanes 0,2,4,6 -> jj 0..3
            st_u64_agent(hbuf64 + (size_t)group * 1024 + j_l,
                         ((unsigned long long)hi << 32) | lo);
        if (lane < 8)
            out[((size_t)b_l * 2048) * 1024 + j_l] = hnew;
    }

    for (int t = 1; t < T_STEPS; t++) {
        // gx prefetch (cached loads, hidden under the staging/poll)
        const size_t xb = ((size_t)b_l * 2048 + t) * 3072 + j_l;
        const float gxr = xproj[xb];
        const float gxz = xproj[xb + 1024];
        const float gxn = xproj[xb + 2048];

        // ---- stage h(t-1): 4 packed tagged u64 loads per thread ----
        const int par = (t - 1) & 1;
        const unsigned long long* src =
            hbuf64 + (size_t)par * 4096 + (size_t)group * 1024;
        const unsigned expect = (((unsigned)(t - 1) >> 1) & 1u) ^ 1u;
        unsigned long long v[4];
#pragma unroll
        for (int i = 0; i < 4; i++)
            v[i] = ld_u64_agent(src + tid + 256 * i);
        for (;;) {
            unsigned bad = 0;
#pragma unroll
            for (int i = 0; i < 4; i++)
                bad |= (((unsigned)(v[i] >> 30)) & 1u) ^ expect;
            if (bad == 0) break;
            __builtin_amdgcn_s_sleep(1);
#pragma unroll
            for (int i = 0; i < 4; i++)
                if ((((unsigned)(v[i] >> 30)) & 1u) != expect)
                    v[i] = ld_u64_agent(src + tid + 256 * i);
        }
#pragma unroll
        for (int i = 0; i < 4; i++) {
            const int s = tid + 256 * i;    // slot = j
            hshare[par][0][s] = __uint_as_float((unsigned)v[i] & 0xBFFFFFFFu);
            hshare[par][1][s] = __uint_as_float((unsigned)(v[i] >> 32));
        }
        __syncthreads();   // whole block validated + staged h(t-1)
        // (no trailing barrier: next step stages into the other parity half)

        const float hprev = hshare[par][bb_l][j_l];

        // hv held in regs across the matvec: 8 ds_read_b128
        f32x4 hv[2][4];
#pragma unroll
        for (int bb = 0; bb < 2; bb++)
#pragma unroll
            for (int m = 0; m < 4; m++)
                hv[bb][m] = *reinterpret_cast<const f32x4*>(
                    &hshare[par][bb][4 * lane + 256 * m]);

        // ---- matvec: 3 gates x 4 j x 2 b x 16 k = 384 FMA, compiler-scheduled
        // (the sunk wf loads interleave freely with FMAs and the poll above) ----
        float acc[3][8];   // [g][jj*2+bb]
#pragma unroll
        for (int g = 0; g < 3; g++)
#pragma unroll
            for (int q = 0; q < 8; q++) acc[g][q] = 0.f;
#pragma unroll
        for (int jj = 0; jj < 4; jj++)
#pragma unroll
            for (int bb = 0; bb < 2; bb++)
#pragma unroll
                for (int m = 0; m < 4; m++)
#pragma unroll
                    for (int e = 0; e < 4; e++) {
                        acc[0][jj * 2 + bb] = fmaf(wf[0][jj][m][e],
                            hv[bb][m][e], acc[0][jj * 2 + bb]);
                        acc[1][jj * 2 + bb] = fmaf(wf[1][jj][m][e],
                            hv[bb][m][e], acc[1][jj * 2 + bb]);
                        acc[2][jj * 2 + bb] = fmaf(wf[2][jj][m][e],
                            hv[bb][m][e], acc[2][jj * 2 + bb]);
                    }

        // ---- value-folding reduce over the 64-way K split ----
        // fold bb vs lane-bit0, jj-bit0 vs lane-bit1, jj-bit1 vs lane-bit2,
        // then butterflies 8/16/32; lane l ends with full sums for c = l&7.
        float a4[3][4];
#pragma unroll
        for (int g = 0; g < 3; g++)
#pragma unroll
            for (int k = 0; k < 4; k++) {
                const float e = acc[g][2 * k], o = acc[g][2 * k + 1];
                const float give = (lane & 1) ? e : o;
                const float keep = (lane & 1) ? o : e;
                a4[g][k] = keep + __shfl_xor(give, 1);
            }
        float a2[3][2];
#pragma unroll
        for (int g = 0; g < 3; g++)
#pragma unroll
            for (int k = 0; k < 2; k++) {
                const float e = a4[g][2 * k], o = a4[g][2 * k + 1];
                const float give = (lane & 2) ? e : o;
                const float keep = (lane & 2) ? o : e;
                a2[g][k] = keep + __shfl_xor(give, 2);
            }
        float a1[3];
#pragma unroll
        for (int g = 0; g < 3; g++) {
            const float e = a2[g][0], o = a2[g][1];
            const float give = (lane & 4) ? e : o;
            const float keep = (lane & 4) ? o : e;
            a1[g] = keep + __shfl_xor(give, 4);
        }
#pragma unroll
        for (int m = 8; m <= 32; m <<= 1)
#pragma unroll
            for (int g = 0; g < 3; g++) a1[g] += __shfl_xor(a1[g], m);

        // ---- gates on all lanes (a1 valid for c = lane&7 on every lane) ----
        const float r = sigmoidf_(gxr + a1[0] + bh0);
        const float z = sigmoidf_(gxz + a1[1] + bh1);
        const float n = tanhf(gxn + r * (a1[2] + bh2));
        float hnew = (1.f - z) * n + z * hprev;
        hnew = fminf(fmaxf(hnew, -CL), CL);
        const float hpair = __shfl_xor(hnew, 1);
        const unsigned tagst = (((unsigned)t >> 1) & 1u) ^ 1u;
        const unsigned lo = __float_as_uint(hnew) | (tagst << 30);
        const unsigned hi = __float_as_uint(hpair);
        if (lane < 8 && (lane & 1) == 0)
            st_u64_agent(hbuf64 + (size_t)(t & 1) * 4096 +
                             (size_t)group * 1024 + j_l,
                         ((unsigned long long)hi << 32) | lo);
        if (lane < 8)
            out[((size_t)b_l * 2048 + t) * 1024 + j_l] = hnew;
    }
}

extern "C" void kernel_launch(void* const* d_in, const int* in_sizes, int n_in,
                              void* d_out, int out_size, void* d_ws,
                              size_t ws_size, hipStream_t stream) {
    const float* x    = (const float*)d_in[0];
    const float* Wih  = (const float*)d_in[1];
    const float* bih  = (const float*)d_in[2];
    const float* Whh  = (const float*)d_in[3];
    const float* bhh  = (const float*)d_in[4];
    float* outp = (float*)d_out;

    float* xproj = (float*)d_ws;
    unsigned long long* hbuf64 =
        (unsigned long long*)((char*)d_ws + HBUF64_BYTE_OFF);

    dim3 g1(128, 24);   // M/128, N/128
    gemm_xproj<<<g1, 256, 0, stream>>>(x, Wih, bih, xproj);
    gru_scan<<<256, 256, 0, stream>>>(Whh, bhh, xproj, outp, hbuf64);
}